// Round 3
// baseline (209.572 us; speedup 1.0000x reference)
//
#include <hip/hip_runtime.h>
#include <math.h>

#define DD 64
#define LL 2048
#define TQ 128
#define TK 64
#define NT 256
// 1/sqrt(64) * log2(e), folded into Q at staging (leaky commutes with positive scale)
#define QSCALE 0.18033688011112042f

typedef __bf16 bf16_t;
typedef __bf16 bf16x8 __attribute__((ext_vector_type(8)));
typedef __bf16 bf16x4 __attribute__((ext_vector_type(4)));
typedef float f32x16 __attribute__((ext_vector_type(16)));

// rows padded to 72 elems = 144 B = 9*16B: b128-aligned rows, +4 banks/row rotation
struct __align__(16) SMemA {
  bf16_t Qs[TQ][72];   // [lq][d] transposed, pre-scaled by QSCALE
  bf16_t Ks[TK][72];   // [lk][d] transposed
  bf16_t Vs[DD][72];   // [d][lk] natural
};
union __align__(16) SMemU {
  SMemA a;
  float Oe[TQ][65];    // epilogue transpose buffer
};

__global__ __launch_bounds__(256, 2)
void attn_flash_bf16(const float* __restrict__ q, const float* __restrict__ k,
                     const float* __restrict__ v, float* __restrict__ out) {
  __shared__ SMemU sm;
  __shared__ float rs[TQ];
  const int tid  = threadIdx.x;
  const int w    = tid >> 6;       // wave 0..3, owns lq strip [w*32, w*32+32)
  const int lane = tid & 63;
  const int l31  = lane & 31;
  const int hh   = lane >> 5;      // half 0/1
  const int head = blockIdx.y;
  const int q0   = blockIdx.x * TQ;
  const size_t hoff = (size_t)head * DD * LL;
  const float* qp = q + hoff;
  const float* kp = k + hoff;
  const float* vp = v + hoff;

  // ---- stage Q transposed once: thread = (row lq, 32-d range); b128 writes (conflict-free) ----
  {
    int lq = tid & 127;
    int d0 = (tid >> 7) * 32;
    const float* src = qp + q0 + lq;
    for (int g = 0; g < 4; ++g) {
      bf16x8 pk;
      for (int j = 0; j < 8; ++j)
        pk[j] = (bf16_t)(src[(size_t)(d0 + g * 8 + j) * LL] * QSCALE);
      *(bf16x8*)&sm.a.Qs[lq][d0 + g * 8] = pk;
    }
  }
  __syncthreads();

  const int wbase = w * 32;
  // hoist Q B-fragments: B[n=lq=l31][k=d], k-chunk = kk*16 + 8*hh
  bf16x8 bq[4];
  for (int kk = 0; kk < 4; ++kk)
    bq[kk] = *(const bf16x8*)&sm.a.Qs[wbase + l31][kk * 16 + 8 * hh];

  f32x16 oacc[2];
  for (int dt = 0; dt < 2; ++dt)
    for (int r = 0; r < 16; ++r) oacc[dt][r] = 0.f;
  float rsum = 0.f;

  for (int t = 0; t < LL / TK; ++t) {
    const int lk0 = t * TK;
    __syncthreads();  // prior tile's Ks/Vs reads done before restage
    // ---- K transposed: thread = (row lk, 16-d range); scalar coalesced loads, b128 writes ----
    {
      int lk = tid & 63;
      int d0 = (tid >> 6) * 16;
      const float* src = kp + lk0 + lk;
      for (int g = 0; g < 2; ++g) {
        bf16x8 pk;
        for (int j = 0; j < 8; ++j)
          pk[j] = (bf16_t)src[(size_t)(d0 + g * 8 + j) * LL];
        *(bf16x8*)&sm.a.Ks[lk][d0 + g * 8] = pk;
      }
    }
    // ---- V natural: float4 loads, b64 writes (conflict-free) ----
    for (int i = 0; i < 4; ++i) {
      int idx = tid + NT * i;          // 0..1023
      int d   = idx >> 4;              // 0..63
      int c4  = (idx & 15) * 4;        // lk 0..60
      float4 vv = *(const float4*)(vp + (size_t)d * LL + lk0 + c4);
      bf16x4 pk;
      pk[0] = (bf16_t)vv.x; pk[1] = (bf16_t)vv.y;
      pk[2] = (bf16_t)vv.z; pk[3] = (bf16_t)vv.w;
      *(bf16x4*)&sm.a.Vs[d][c4] = pk;
    }
    __syncthreads();

    // ---- S^T = K^T Q : A[m=lk]=Ks rows, B[n=lq]=bq; C col=lq(lane), rows=lk(regs) ----
    f32x16 st[2];
    for (int nt = 0; nt < 2; ++nt)
      for (int r = 0; r < 16; ++r) st[nt][r] = 0.f;
    for (int nt = 0; nt < 2; ++nt)
      for (int kk = 0; kk < 4; ++kk) {
        bf16x8 ak = *(const bf16x8*)&sm.a.Ks[nt * 32 + l31][kk * 16 + 8 * hh];
        st[nt] = __builtin_amdgcn_mfma_f32_32x32x16_bf16(ak, bq[kk], st[nt], 0, 0, 0);
      }

    // ---- leaky + exp2 in registers (Q pre-scaled); pack to bf16 pairs ----
    unsigned pb[2][8];
    for (int nt = 0; nt < 2; ++nt) {
      for (int r = 0; r < 16; ++r) {
        float s = st[nt][r];
        s = fmaxf(s, 0.01f * s);
        float p = __builtin_amdgcn_exp2f(s);
        rsum += p;
        st[nt][r] = p;
      }
      for (int qq = 0; qq < 8; ++qq) {
        union { bf16_t b[2]; unsigned u; } pk;
        pk.b[0] = (bf16_t)st[nt][2 * qq];
        pk.b[1] = (bf16_t)st[nt][2 * qq + 1];
        pb[nt][qq] = pk.u;
      }
    }

    // ---- PV: A[m=lq][k=lk] built from st via one cross-half exchange per pair ----
    for (int nt = 0; nt < 2; ++nt)
      for (int kk2 = 0; kk2 < 2; ++kk2) {
        unsigned l0 = pb[nt][4 * kk2 + 0], l1 = pb[nt][4 * kk2 + 1];
        unsigned l2 = pb[nt][4 * kk2 + 2], l3 = pb[nt][4 * kk2 + 3];
        unsigned s0 = hh ? l0 : l2;
        unsigned s1 = hh ? l1 : l3;
        unsigned f0 = (unsigned)__shfl_xor((int)s0, 32);
        unsigned f1 = (unsigned)__shfl_xor((int)s1, 32);
        union { unsigned u[4]; bf16x8 v; } ap;
        ap.u[0] = hh ? f0 : l0;
        ap.u[1] = hh ? f1 : l1;
        ap.u[2] = hh ? l2 : f0;
        ap.u[3] = hh ? l3 : f1;
        const int lkb = nt * 32 + kk2 * 16 + 8 * hh;
        for (int dt = 0; dt < 2; ++dt) {
          bf16x8 bv = *(const bf16x8*)&sm.a.Vs[dt * 32 + l31][lkb];
          oacc[dt] = __builtin_amdgcn_mfma_f32_32x32x16_bf16(ap.v, bv, oacc[dt], 0, 0, 0);
        }
      }
  }

  // ---- row-sum finalize: one cross-half add; broadcast inverse via tiny LDS array ----
  float rtot = rsum + __shfl_xor(rsum, 32);
  rs[wbase + l31] = 1.0f / rtot;   // wave-private rows; lgkmcnt ordering within wave
  float inv[16];
  for (int r = 0; r < 16; ++r) {
    int row = (r & 3) + 8 * (r >> 2) + 4 * hh;
    inv[r] = rs[wbase + row];      // broadcast reads
  }
  __syncthreads();  // all PV-era LDS reads done before union overwrite
  for (int r = 0; r < 16; ++r) {
    int row = (r & 3) + 8 * (r >> 2) + 4 * hh;
    for (int dt = 0; dt < 2; ++dt)
      sm.Oe[wbase + row][dt * 32 + l31] = oacc[dt][r] * inv[r];
  }
  __syncthreads();
  float* op = out + hoff + q0;
  for (int i = 0; i < 32; ++i) {
    int idx = tid + NT * i;   // 0..8191
    int d   = idx >> 7;       // 0..63
    int lq  = idx & 127;
    op[(size_t)d * LL + lq] = sm.Oe[lq][d];  // coalesced: lanes -> consecutive lq
  }
}

extern "C" void kernel_launch(void* const* d_in, const int* in_sizes, int n_in,
                              void* d_out, int out_size, void* d_ws, size_t ws_size,
                              hipStream_t stream) {
  const float* q = (const float*)d_in[0];
  const float* k = (const float*)d_in[1];
  const float* v = (const float*)d_in[2];
  float* out = (float*)d_out;
  dim3 grid(LL / TQ, 32);  // 16 q-tiles x (B*H=32)
  attn_flash_bf16<<<grid, 256, 0, stream>>>(q, k, v, out);
}

// Round 4
// 145.738 us; speedup vs baseline: 1.4380x; 1.4380x over previous
//
#include <hip/hip_runtime.h>
#include <math.h>

#define DD 64
#define LL 2048
#define TQ 128
#define TK 64
#define NTHREADS 512
// 1/sqrt(64) * log2(e), folded into Q at staging (leaky commutes with positive scale)
#define QSCALE 0.18033688011112042f

typedef __bf16 bf16_t;
typedef __bf16 bf16x8 __attribute__((ext_vector_type(8)));
typedef float f32x16 __attribute__((ext_vector_type(16)));

// rows padded to 72 elems = 144 B = 9*16B: b128-aligned rows, +4 banks/row rotation
struct __align__(16) SMemA {
  bf16_t Qs[TQ][72];   // [lq][d] transposed, pre-scaled by QSCALE
  bf16_t Ks[TK][72];   // [lk][d] transposed
  bf16_t Vs[DD][72];   // [d][lk] natural
};
union __align__(16) SMemU {
  SMemA a;
  float Oe[TQ][65];    // epilogue combine/transpose buffer (fp32)
};

__global__ __launch_bounds__(NTHREADS, 4)
void attn_flash_bf16(const float* __restrict__ q, const float* __restrict__ k,
                     const float* __restrict__ v, float* __restrict__ out) {
  __shared__ SMemU sm;
  __shared__ float rs1[TQ];   // half-1 partial row sums
  const int tid  = threadIdx.x;
  const int w    = tid >> 6;        // wave 0..7
  const int lane = tid & 63;
  const int l31  = lane & 31;
  const int hh   = lane >> 5;       // half of wave
  const int strip = w & 3;          // lq strip 0..3
  const int half  = w >> 2;         // lk half 0/1
  const int wbase = strip * 32;
  const int lkh   = half * 32;
  const int head = blockIdx.y;
  const int q0   = blockIdx.x * TQ;
  const size_t hoff = (size_t)head * DD * LL;
  const float* qp = q + hoff;
  const float* kp = k + hoff;
  const float* vp = v + hoff;

  // ---- stage Q transposed once: thread=(lq, 16-d range); b128 writes (2-way, free) ----
  {
    int lq  = tid & 127;
    int d0q = (tid >> 7) * 16;
    const float* src = qp + q0 + lq;
    for (int g = 0; g < 2; ++g) {
      bf16x8 pk;
      for (int j = 0; j < 8; ++j)
        pk[j] = (bf16_t)(src[(size_t)(d0q + g * 8 + j) * LL] * QSCALE);
      *(bf16x8*)&sm.a.Qs[lq][d0q + g * 8] = pk;
    }
  }

  // staging coordinates (per tile): K transpose + V natural
  const int klk = tid & 63;             // K: this thread's lk row
  const int kd0 = (tid >> 6) * 8;       // K: 8-d range
  const int vd  = tid >> 3;             // V: d row 0..63
  const int vc8 = (tid & 7) * 8;        // V: 8-lk range

  // ---- prefetch tile 0 into registers ----
  float  kreg[8];
  float4 vreg[2];
  {
    const float* ks = kp + klk;
    for (int j = 0; j < 8; ++j) kreg[j] = ks[(size_t)(kd0 + j) * LL];
    vreg[0] = *(const float4*)(vp + (size_t)vd * LL + vc8);
    vreg[1] = *(const float4*)(vp + (size_t)vd * LL + vc8 + 4);
  }

  __syncthreads();   // Q staged
  // hoist Q B-fragments: B[n=lq=wbase+l31][k=d], k-chunk = kk*16 + 8*hh
  bf16x8 bq[4];
  for (int kk = 0; kk < 4; ++kk)
    bq[kk] = *(const bf16x8*)&sm.a.Qs[wbase + l31][kk * 16 + 8 * hh];

  f32x16 oacc[2];
  for (int dt = 0; dt < 2; ++dt)
    for (int r = 0; r < 16; ++r) oacc[dt][r] = 0.f;
  float rsum = 0.f;

  for (int t = 0; t < LL / TK; ++t) {
    __syncthreads();  // prior tile's Ks/Vs reads done
    // ---- commit prefetched K (transposed) + V (natural) to LDS ----
    {
      bf16x8 pk;
      for (int j = 0; j < 8; ++j) pk[j] = (bf16_t)kreg[j];
      *(bf16x8*)&sm.a.Ks[klk][kd0] = pk;
      bf16x8 pv;
      pv[0] = (bf16_t)vreg[0].x; pv[1] = (bf16_t)vreg[0].y;
      pv[2] = (bf16_t)vreg[0].z; pv[3] = (bf16_t)vreg[0].w;
      pv[4] = (bf16_t)vreg[1].x; pv[5] = (bf16_t)vreg[1].y;
      pv[6] = (bf16_t)vreg[1].z; pv[7] = (bf16_t)vreg[1].w;
      *(bf16x8*)&sm.a.Vs[vd][vc8] = pv;
    }
    __syncthreads();

    // ---- issue prefetch for tile t+1 (in flight during compute) ----
    if (t + 1 < LL / TK) {
      const int lk0n = (t + 1) * TK;
      const float* ks = kp + lk0n + klk;
      for (int j = 0; j < 8; ++j) kreg[j] = ks[(size_t)(kd0 + j) * LL];
      vreg[0] = *(const float4*)(vp + (size_t)vd * LL + lk0n + vc8);
      vreg[1] = *(const float4*)(vp + (size_t)vd * LL + lk0n + vc8 + 4);
    }

    // ---- S^T = K^T Q over this wave's lk half: C col=lq(lane), rows=lk(regs) ----
    f32x16 st;
    for (int r = 0; r < 16; ++r) st[r] = 0.f;
    for (int kk = 0; kk < 4; ++kk) {
      bf16x8 ak = *(const bf16x8*)&sm.a.Ks[lkh + l31][kk * 16 + 8 * hh];
      st = __builtin_amdgcn_mfma_f32_32x32x16_bf16(ak, bq[kk], st, 0, 0, 0);
    }

    // ---- leaky + exp2 in registers; pack pairs for PV A-operand ----
    unsigned pb[8];
    for (int r = 0; r < 16; ++r) {
      float s = st[r];
      s = fmaxf(s, 0.01f * s);
      float p = __builtin_amdgcn_exp2f(s);
      rsum += p;
      st[r] = p;
    }
    for (int qq = 0; qq < 8; ++qq) {
      union { bf16_t b[2]; unsigned u; } pk;
      pk.b[0] = (bf16_t)st[2 * qq];
      pk.b[1] = (bf16_t)st[2 * qq + 1];
      pb[qq] = pk.u;
    }

    // ---- PV over this wave's lk half: A[m=lq][k=lk] via one cross-half exchange ----
    for (int kk2 = 0; kk2 < 2; ++kk2) {
      unsigned l0 = pb[4 * kk2 + 0], l1 = pb[4 * kk2 + 1];
      unsigned l2 = pb[4 * kk2 + 2], l3 = pb[4 * kk2 + 3];
      unsigned s0 = hh ? l0 : l2;
      unsigned s1 = hh ? l1 : l3;
      unsigned f0 = (unsigned)__shfl_xor((int)s0, 32);
      unsigned f1 = (unsigned)__shfl_xor((int)s1, 32);
      union { unsigned u[4]; bf16x8 v; } ap;
      ap.u[0] = hh ? f0 : l0;
      ap.u[1] = hh ? f1 : l1;
      ap.u[2] = hh ? l2 : f0;
      ap.u[3] = hh ? l3 : f1;
      const int lkb = lkh + kk2 * 16 + 8 * hh;
      for (int dt = 0; dt < 2; ++dt) {
        bf16x8 bv = *(const bf16x8*)&sm.a.Vs[dt * 32 + l31][lkb];
        oacc[dt] = __builtin_amdgcn_mfma_f32_32x32x16_bf16(ap.v, bv, oacc[dt], 0, 0, 0);
      }
    }
  }

  // ---- epilogue: combine lk-half pairs, normalize, transpose, store ----
  float rtot = rsum + __shfl_xor(rsum, 32);   // both hh row-groups of this wave
  __syncthreads();                            // all compute LDS reads done; union safe
  if (half == 1) {
    rs1[wbase + l31] = rtot;
    for (int r = 0; r < 16; ++r) {
      int row = (r & 3) + 8 * (r >> 2) + 4 * hh;
      for (int dt = 0; dt < 2; ++dt)
        sm.Oe[wbase + row][dt * 32 + l31] = oacc[dt][r];
    }
  }
  __syncthreads();
  if (half == 0) {
    float tot = rtot + rs1[wbase + l31];
    rs1[wbase + l31] = 1.0f / tot;            // same-lane read-then-write: safe in-wave
    float inv[16];
    for (int r = 0; r < 16; ++r) {
      int row = (r & 3) + 8 * (r >> 2) + 4 * hh;
      inv[r] = rs1[wbase + row];              // in-wave broadcast reads
    }
    for (int r = 0; r < 16; ++r) {
      int row = (r & 3) + 8 * (r >> 2) + 4 * hh;
      for (int dt = 0; dt < 2; ++dt) {
        int col = dt * 32 + l31;
        sm.Oe[wbase + row][col] = (oacc[dt][r] + sm.Oe[wbase + row][col]) * inv[r];
      }
    }
  }
  __syncthreads();
  float* op = out + hoff + q0;
  for (int i = 0; i < 16; ++i) {
    int idx = tid + NTHREADS * i;  // 0..8191
    int d   = idx >> 7;
    int lq  = idx & 127;
    op[(size_t)d * LL + lq] = sm.Oe[lq][d];   // coalesced: lanes -> consecutive lq
  }
}

extern "C" void kernel_launch(void* const* d_in, const int* in_sizes, int n_in,
                              void* d_out, int out_size, void* d_ws, size_t ws_size,
                              hipStream_t stream) {
  const float* q = (const float*)d_in[0];
  const float* k = (const float*)d_in[1];
  const float* v = (const float*)d_in[2];
  float* out = (float*)d_out;
  dim3 grid(LL / TQ, 32);  // 16 q-tiles x (B*H=32)
  attn_flash_bf16<<<grid, NTHREADS, 0, stream>>>(q, k, v, out);
}